// Round 2
// baseline (149.018 us; speedup 1.0000x reference)
//
#include <hip/hip_runtime.h>
#include <hip/hip_bf16.h>
#include <math.h>

// Problem constants
#define BATCH   2048
#define TWO_B   4096
#define DIM     1024
#define NB      32            // 4096 / 128 tile blocks per side
#define NTRI    528           // NB*(NB+1)/2 upper-triangle blocks
// 1 / (0.07 * ln(2)) : exp(s/T) = exp2(s * INV_T_LOG2E)
#define INV_T_LOG2E 20.60991907f
#define INV_T       14.285714285714286f

typedef __bf16  bf16x8 __attribute__((ext_vector_type(8)));
typedef float   f32x4  __attribute__((ext_vector_type(4)));

__device__ __forceinline__ unsigned short f2bf(float f) {
    union { float f; unsigned int u; } x; x.f = f;
    unsigned int u = x.u;
    return (unsigned short)((u + 0x7fffu + ((u >> 16) & 1u)) >> 16); // RNE
}

__device__ __forceinline__ void load_lds16(const void* g, void* l) {
    __builtin_amdgcn_global_load_lds(
        (const __attribute__((address_space(1))) void*)g,
        (__attribute__((address_space(3))) void*)l,
        16, 0, 0);
}

// ---------------------------------------------------------------------------
// Kernel 1: L2-normalize each of the 4096 rows, write bf16 z[4096][1024].
// Also zero-inits rowsum[row] and (block 0) the completion counter —
// same-stream dispatch ordering makes these visible to the GEMM kernel.
// ---------------------------------------------------------------------------
__global__ __launch_bounds__(256) void normalize_kernel(
        const float* __restrict__ feat, unsigned short* __restrict__ z,
        float* __restrict__ rowsum, unsigned int* __restrict__ counter) {
    const int row = blockIdx.x;
    const int tid = threadIdx.x;
    if (tid == 0) rowsum[row] = 0.0f;
    if (row == 0 && tid == 1) *counter = 0u;
    const float* src = feat + (row < BATCH ? (size_t)row * (2 * DIM)
                                           : (size_t)(row - BATCH) * (2 * DIM) + DIM);
    float4 v = ((const float4*)src)[tid];
    float ss = v.x * v.x + v.y * v.y + v.z * v.z + v.w * v.w;
    #pragma unroll
    for (int off = 32; off; off >>= 1) ss += __shfl_down(ss, off, 64);
    __shared__ float s_part[4];
    if ((tid & 63) == 0) s_part[tid >> 6] = ss;
    __syncthreads();
    float total = s_part[0] + s_part[1] + s_part[2] + s_part[3];
    float scale = 1.0f / fmaxf(sqrtf(total), 1e-12f);
    ushort4 o;
    o.x = f2bf(v.x * scale);
    o.y = f2bf(v.y * scale);
    o.z = f2bf(v.z * scale);
    o.w = f2bf(v.w * scale);
    ((ushort4*)(z + (size_t)row * DIM))[tid] = o;
}

// ---------------------------------------------------------------------------
// Kernel 2: upper-triangle blocks of sim = z z^T (bf16 MFMA, 128x128 tile,
// BK=32) with XOR-swizzled LDS (conflict-free ds_read_b128) + epilogue:
//   rowsum[r] += sum exp(sim/T)  and, for off-diag blocks, rowsum[c] too
//   positives[r] / positives[r+2048] captured where c == r + 2048.
// Last block (device-scope counter) computes the final scalar loss.
// ---------------------------------------------------------------------------
__global__ __launch_bounds__(256) void gemm_fused(
        const unsigned short* __restrict__ z,
        float* __restrict__ rowsum,
        float* __restrict__ positives,
        unsigned int* __restrict__ counter,
        float* __restrict__ out) {
    __shared__ __bf16 sA[128 * 32];
    __shared__ __bf16 sB[128 * 32];

    // exact triangular decode: block idx -> (by, bx) with bx >= by
    int rem = blockIdx.x, by = 0;
    while (rem >= NB - by) { rem -= NB - by; ++by; }
    const int bx = by + rem;
    const int rb = by * 128, cb = bx * 128;
    const bool offdiag = (bx > by);

    const int tid  = threadIdx.x;
    const int lane = tid & 63;
    const int wv   = tid >> 6;       // wave 0..3
    const int wr   = wv >> 1;        // wave row (0..1) -> 64-row subtile
    const int wc   = wv & 1;         // wave col (0..1) -> 64-col subtile
    const int q    = lane >> 4;      // quad 0..3 (K-segment for fragments)
    const int mn   = lane & 15;      // m (A) / n (B) index

    f32x4 acc[4][4] = {};

    const char* zb   = (const char*)z;                 // row stride = 2048 B
    const int ci0    = wv * 2;                         // this wave's 2 chunks
    const int lrow   = lane >> 2;                      // row within 16-row chunk
    // swizzled source segment so LDS slot (l&3) of row (l>>2) holds segment
    // (l&3) ^ ((l>>3)&3): read offset slot = q ^ ((row>>1)&3) is conflict-free
    const int lsegb  = (((lane & 3) ^ ((lane >> 3) & 3)) * 16);
    const int rslot  = (q ^ ((mn >> 1) & 3)) * 8;      // element offset in row

    for (int k0 = 0; k0 < DIM; k0 += 32) {
        #pragma unroll
        for (int t = 0; t < 2; ++t) {
            const int ci = ci0 + t;                    // chunk 0..7, 16 rows
            const char* gA = zb + (size_t)(rb + ci * 16 + lrow) * 2048 + k0 * 2 + lsegb;
            const char* gB = zb + (size_t)(cb + ci * 16 + lrow) * 2048 + k0 * 2 + lsegb;
            load_lds16(gA, (char*)sA + ci * 1024);     // dest = base + lane*16
            load_lds16(gB, (char*)sB + ci * 1024);
        }
        __syncthreads();

        bf16x8 af[4], bfv[4];
        #pragma unroll
        for (int i = 0; i < 4; ++i) {
            af[i]  = *(const bf16x8*)&sA[(wr * 64 + i * 16 + mn) * 32 + rslot];
            bfv[i] = *(const bf16x8*)&sB[(wc * 64 + i * 16 + mn) * 32 + rslot];
        }
        #pragma unroll
        for (int i = 0; i < 4; ++i)
            #pragma unroll
            for (int j = 0; j < 4; ++j)
                acc[i][j] = __builtin_amdgcn_mfma_f32_16x16x32_bf16(
                                af[i], bfv[j], acc[i][j], 0, 0, 0);
        __syncthreads();
    }

    // Epilogue: C/D layout col = lane&15, row = (lane>>4)*4 + reg
    float colAcc[4] = {0.f, 0.f, 0.f, 0.f};
    #pragma unroll
    for (int i = 0; i < 4; ++i) {
        #pragma unroll
        for (int reg = 0; reg < 4; ++reg) {
            const int r = rb + wr * 64 + i * 16 + q * 4 + reg;
            float local = 0.0f;
            #pragma unroll
            for (int j = 0; j < 4; ++j) {
                const int c = cb + wc * 64 + j * 16 + mn;
                const float s = acc[i][j][reg];
                if (r < BATCH && c == r + BATCH) {   // positive pair (and mirror)
                    __hip_atomic_store(&positives[r], s, __ATOMIC_RELAXED,
                                       __HIP_MEMORY_SCOPE_AGENT);
                    __hip_atomic_store(&positives[c], s, __ATOMIC_RELAXED,
                                       __HIP_MEMORY_SCOPE_AGENT);
                }
                const float e = (c == r) ? 0.0f : exp2f(s * INV_T_LOG2E);
                local += e;
                colAcc[j] += e;
            }
            local += __shfl_xor(local, 1, 64);
            local += __shfl_xor(local, 2, 64);
            local += __shfl_xor(local, 4, 64);
            local += __shfl_xor(local, 8, 64);
            if (mn == 0) atomicAdd(&rowsum[r], local);
        }
    }
    if (offdiag) {   // mirror contribution: rowsum[c] += same exp values
        #pragma unroll
        for (int j = 0; j < 4; ++j) {
            float v = colAcc[j];
            v += __shfl_xor(v, 16, 64);
            v += __shfl_xor(v, 32, 64);
            if (q == 0) atomicAdd(&rowsum[cb + wc * 64 + j * 16 + mn], v);
        }
    }

    // ---- last-block finalize (threadfence-reduction pattern, agent scope) ----
    __shared__ int amLast;
    __threadfence();
    __syncthreads();
    if (tid == 0) {
        unsigned int old = atomicAdd(counter, 1u);
        amLast = (old == NTRI - 1);
    }
    __syncthreads();
    if (amLast) {
        __threadfence();
        float acc2 = 0.0f;
        for (int r = tid; r < TWO_B; r += 256) {
            float rs = __hip_atomic_load(&rowsum[r], __ATOMIC_RELAXED,
                                         __HIP_MEMORY_SCOPE_AGENT);
            float p  = __hip_atomic_load(&positives[r], __ATOMIC_RELAXED,
                                         __HIP_MEMORY_SCOPE_AGENT);
            acc2 += logf(rs) - p * INV_T;
        }
        #pragma unroll
        for (int off = 32; off; off >>= 1) acc2 += __shfl_down(acc2, off, 64);
        __shared__ float s_part[4];
        if ((tid & 63) == 0) s_part[tid >> 6] = acc2;
        __syncthreads();
        if (tid == 0)
            out[0] = (s_part[0] + s_part[1] + s_part[2] + s_part[3]) * (1.0f / TWO_B);
    }
}

extern "C" void kernel_launch(void* const* d_in, const int* in_sizes, int n_in,
                              void* d_out, int out_size, void* d_ws, size_t ws_size,
                              hipStream_t stream) {
    const float* feat = (const float*)d_in[0];
    char* ws = (char*)d_ws;

    // workspace: z bf16[4096][1024] (8 MB) | rowsum f32[4096] | positives f32[4096] | counter
    unsigned short* z     = (unsigned short*)ws;
    float* rowsum         = (float*)(ws + (size_t)TWO_B * DIM * 2);
    float* positives      = rowsum + TWO_B;
    unsigned int* counter = (unsigned int*)(positives + TWO_B);
    float* out            = (float*)d_out;

    normalize_kernel<<<TWO_B, 256, 0, stream>>>(feat, z, rowsum, counter);
    gemm_fused<<<NTRI, 256, 0, stream>>>(z, rowsum, positives, counter, out);
}